// Round 9
// baseline (451.615 us; speedup 1.0000x reference)
//
#include <hip/hip_runtime.h>
#include <hip/hip_cooperative_groups.h>
#include <stdint.h>

#define S_LEN 4096
#define SCALE_LOG2E 0.18033688011112042f   // (1/sqrt(64)) * log2(e), folded into Q

typedef __attribute__((ext_vector_type(8))) short bf16x8;
typedef __attribute__((ext_vector_type(4))) float f32x4;

#if __has_builtin(__builtin_amdgcn_exp2f)
#define EXP2(x) __builtin_amdgcn_exp2f(x)
#else
#define EXP2(x) exp2f(x)
#endif

#if __has_builtin(__builtin_amdgcn_sbfe)
#define SBFE1(x, o) __builtin_amdgcn_sbfe((int)(x), (o), 1)
#else
#define SBFE1(x, o) (((int)((unsigned)(x) << (31 - (o)))) >> 31)
#endif

__device__ __forceinline__ unsigned pk2(float a, float b) {
    // round-half-up bf16 pair pack: +0x8000 then take high halves via v_perm
    unsigned ua = __builtin_bit_cast(unsigned, a) + 0x8000u;
    unsigned ub = __builtin_bit_cast(unsigned, b) + 0x8000u;
    return __builtin_amdgcn_perm(ub, ua, 0x07060302u);
}

// packed f32->bf16 pair (lo = a, hi = b), single instruction
__device__ __forceinline__ unsigned cvtpk(float a, float b) {
    unsigned r;
    asm("v_cvt_pk_bf16_f32 %0, %1, %2" : "=v"(r) : "v"(a), "v"(b));
    return r;
}

__device__ __forceinline__ f32x4 mfma16(bf16x8 a, bf16x8 b, f32x4 c) {
    return __builtin_amdgcn_mfma_f32_16x16x32_bf16(a, b, c, 0, 0, 0);
}

__device__ __forceinline__ bf16x8 bf16_ones() {
    uint4 q = {0x3F803F80u, 0x3F803F80u, 0x3F803F80u, 0x3F803F80u};
    return __builtin_bit_cast(bf16x8, q);
}

// async 16B global->LDS copy (LDS dest = wave-uniform base + lane*16)
__device__ __forceinline__ void gld16(const void* g, void* l) {
    __builtin_amdgcn_global_load_lds(
        (const __attribute__((address_space(1))) unsigned*)g,
        (__attribute__((address_space(3))) unsigned*)l, 16, 0, 0);
}

// ------------- mask packing: bool(any encoding) -> bitfield, [kt][q] layout --
// Grid-stride over 16384 logical blocks (2048 launched x 8).
__global__ __launch_bounds__(256) void pack_mask_kernel(
    const unsigned* __restrict__ m32, unsigned long long* __restrict__ out) {
    const int lane = threadIdx.x & 63;
    const int w = threadIdx.x >> 6;
    unsigned pv = m32[lane];
    bool okw = (pv == 0u) || (pv == 1u) || (pv == 0x3F800000u);
    const bool is_word = (__ballot(okw) == ~0ull);
    const unsigned char* m8 = (const unsigned char*)m32;
    for (int bx = blockIdx.x; bx < 16384; bx += gridDim.x) {
        const long long wbase = ((long long)bx * 4 + w) * 4;   // u64 words (q*64+kt)
#pragma unroll
        for (int it = 0; it < 4; ++it) {
            const long long word = wbase + it;
            long long e = word * 64 + lane;
            bool bit = is_word ? (m32[e] != 0u) : (m8[e] != 0);
            unsigned long long bal = __ballot(bit);
            if (lane == 0) {
                long long q = word >> 6, kt = word & 63;
                out[kt * S_LEN + q] = bal;   // transposed: coalesced reads in attn
            }
        }
    }
}

// ---------------- staging: global fp32 -> regs (packed bf16), 256 threads ----
__device__ __forceinline__ void pf_load(const float* __restrict__ K,
                                        const float* __restrict__ V,
                                        int bh, int k0, int t,
                                        unsigned* kb, unsigned* vb) {
    const int r = t >> 2, h = t & 3;
    const float* kp = K + (((size_t)(bh * S_LEN + k0 + r)) << 6) + h * 16;
#pragma unroll
    for (int cc = 0; cc < 2; ++cc) {
        float4 f0 = ((const float4*)kp)[cc * 2];
        float4 f1 = ((const float4*)kp)[cc * 2 + 1];
        kb[cc * 4 + 0] = pk2(f0.x, f0.y);
        kb[cc * 4 + 1] = pk2(f0.z, f0.w);
        kb[cc * 4 + 2] = pk2(f1.x, f1.y);
        kb[cc * 4 + 3] = pk2(f1.z, f1.w);
    }
    const int d = t & 63, g = t >> 6;
    const float* vp = V + (((size_t)(bh * S_LEN + k0 + g * 16)) << 6) + d;
#pragma unroll
    for (int c8 = 0; c8 < 2; ++c8) {
        float f[8];
#pragma unroll
        for (int i = 0; i < 8; ++i) f[i] = vp[(c8 * 8 + i) * 64];
        vb[c8 * 4 + 0] = pk2(f[0], f[1]);
        vb[c8 * 4 + 1] = pk2(f[2], f[3]);
        vb[c8 * 4 + 2] = pk2(f[4], f[5]);
        vb[c8 * 4 + 3] = pk2(f[6], f[7]);
    }
}

__device__ __forceinline__ void pf_store(int t, const unsigned* kb, const unsigned* vb,
                                         unsigned short* lk, unsigned short* lv) {
    const int r = t >> 2, h = t & 3;
#pragma unroll
    for (int cc = 0; cc < 2; ++cc) {
        int c = h * 2 + cc;
        uint4 st = {kb[cc * 4 + 0], kb[cc * 4 + 1], kb[cc * 4 + 2], kb[cc * 4 + 3]};
        *(uint4*)&lk[r * 64 + ((c ^ (r & 7)) << 3)] = st;
    }
    const int d = t & 63, g = t >> 6;
#pragma unroll
    for (int c8 = 0; c8 < 2; ++c8) {
        int c = g * 2 + c8;
        uint4 st = {vb[c8 * 4 + 0], vb[c8 * 4 + 1], vb[c8 * 4 + 2], vb[c8 * 4 + 3]};
        *(uint4*)&lv[d * 64 + ((c ^ (d & 7)) << 3)] = st;
    }
}

// ---------------- pre-pass: fp32 K/V -> bf16 tiles in swizzled LDS layout ----
__global__ __launch_bounds__(256) void kv_convert_kernel(
    const float* __restrict__ K, const float* __restrict__ V,
    unsigned short* __restrict__ kv) {
    const int t = threadIdx.x;
    const int kt = blockIdx.x;     // 64 tiles
    const int bh = blockIdx.y;     // 16
    unsigned kb[8], vb[8];
    pf_load(K, V, bh, kt * 64, t, kb, vb);
    unsigned short* base = kv + ((size_t)(bh * 64 + kt)) * 8192;   // 16 KB / tile
    pf_store(t, kb, vb, base, base + 4096);
}

// async-stage one prepacked 16 KB tile with 8 waves: 2 x gld16 per thread
__device__ __forceinline__ void stage_tile8(const unsigned short* kvtile,
                                            unsigned short* lk, unsigned short* lv,
                                            int tid) {
    const int w = tid >> 6;
    const int lane = tid & 63;
    const char* g = (const char*)kvtile + w * 1024 + lane * 16;
    gld16(g, (char*)lk + w * 1024);            // K half: bytes [0, 8K)
    gld16(g + 8192, (char*)lv + w * 1024);     // V half: bytes [8K, 16K)
}

// ---------------- one 64-key tile: S^T = K·Q^T, softmax, O^T += V^T·P^T ------
// PROVEN R2/R6 STRUCTURE (byte-identical).
template <int USE_PACKED>
__device__ __forceinline__ void compute_tile(
    int kt, int q0w, int n16, int quad,
    const unsigned long long (&mrow)[2],
    const unsigned* __restrict__ rawmask, int mask_is_word,
    const unsigned short* lk, const unsigned short* lv, unsigned short* lp,
    const bf16x8 (&aq)[2][2], f32x4 (&oacc)[4][2], f32x4 (&oaccl)[2]) {
    const int k0 = kt * 64;
    const f32x4 z = {0.f, 0.f, 0.f, 0.f};
    unsigned nmw[2][2];
    if (USE_PACKED) {
#pragma unroll
        for (int nt = 0; nt < 2; ++nt) {
            unsigned long long nm = ~(mrow[nt] >> (quad * 4));
            nmw[nt][0] = (unsigned)nm;
            nmw[nt][1] = (unsigned)(nm >> 32);
        }
    }
#pragma unroll
    for (int mth = 0; mth < 2; ++mth) {
        f32x4 sac[2][2];
#pragma unroll
        for (int mi = 0; mi < 2; ++mi)
#pragma unroll
            for (int nt = 0; nt < 2; ++nt) {
                if (USE_PACKED) {
                    const int mt = mth * 2 + mi;
#pragma unroll
                    for (int reg = 0; reg < 4; ++reg) {
                        unsigned ext = (unsigned)SBFE1(nmw[nt][mt >> 1], (mt & 1) * 16 + reg);
                        sac[mi][nt][reg] = __builtin_bit_cast(float, 0xFF800000u & ext);
                    }
                } else {
                    sac[mi][nt] = z;
                }
            }
        __builtin_amdgcn_s_setprio(1);
#pragma unroll
        for (int kd = 0; kd < 2; ++kd) {
#pragma unroll
            for (int mi = 0; mi < 2; ++mi) {
                int row = (mth * 2 + mi) * 16 + n16;
                bf16x8 ak = *(const bf16x8*)&lk[row * 64 + (((kd * 4 + quad) ^ (row & 7)) << 3)];
#pragma unroll
                for (int nt = 0; nt < 2; ++nt)
                    sac[mi][nt] = mfma16(ak, aq[nt][kd], sac[mi][nt]);
            }
        }
        __builtin_amdgcn_s_setprio(0);
#pragma unroll
        for (int mi = 0; mi < 2; ++mi) {
#pragma unroll
            for (int nt = 0; nt < 2; ++nt) {
                const int mt = mth * 2 + mi;
                float p[4];
#pragma unroll
                for (int reg = 0; reg < 4; ++reg) {
                    float e = EXP2(sac[mi][nt][reg]);
                    if (!USE_PACKED) {
                        int pos = mt * 16 + quad * 4 + reg;
                        size_t mi2 = (size_t)(q0w + nt * 16 + n16) * S_LEN + k0 + pos;
                        bool bit = mask_is_word ? (rawmask[mi2] != 0u)
                                                : (((const unsigned char*)rawmask)[mi2] != 0);
                        e = bit ? e : 0.0f;
                    }
                    p[reg] = e;
                }
                uint2 pr = {cvtpk(p[0], p[1]), cvtpk(p[2], p[3])};
                const int r = nt * 16 + n16;
                const int chunk = (mt * 2 + (quad >> 1)) ^ (n16 & 7);
                *(uint2*)((char*)lp + r * 128 + chunk * 16 + (quad & 1) * 8) = pr;
            }
        }
    }
    const bf16x8 onesv = bf16_ones();
    __builtin_amdgcn_s_setprio(1);
#pragma unroll
    for (int kk = 0; kk < 2; ++kk) {
        bf16x8 av[4];
#pragma unroll
        for (int md = 0; md < 4; ++md) {
            int dr = md * 16 + n16;
            av[md] = *(const bf16x8*)&lv[dr * 64 + (((kk * 4 + quad) ^ (dr & 7)) << 3)];
        }
#pragma unroll
        for (int nt = 0; nt < 2; ++nt) {
            const int r = nt * 16 + n16;
            const int chunk = (kk * 4 + quad) ^ (n16 & 7);
            bf16x8 pb = *(const bf16x8*)((const char*)lp + r * 128 + chunk * 16);
#pragma unroll
            for (int md = 0; md < 4; ++md)
                oacc[md][nt] = mfma16(av[md], pb, oacc[md][nt]);
            oaccl[nt] = mfma16(onesv, pb, oaccl[nt]);   // row sums on MFMA pipe
        }
    }
    __builtin_amdgcn_s_setprio(0);
}

__device__ __forceinline__ void load_q_frags(const float* __restrict__ Q, int bh, int q0w,
                                             int n16, int quad, bf16x8 (&aq)[2][2]) {
#pragma unroll
    for (int nt = 0; nt < 2; ++nt) {
        const float* qp = Q + ((size_t)(bh * S_LEN + q0w + nt * 16 + n16) << 6);
#pragma unroll
        for (int kd = 0; kd < 2; ++kd) {
            float4 f0 = *(const float4*)(qp + kd * 32 + quad * 8);
            float4 f1 = *(const float4*)(qp + kd * 32 + quad * 8 + 4);
            uint4 u = {pk2(f0.x * SCALE_LOG2E, f0.y * SCALE_LOG2E),
                       pk2(f0.z * SCALE_LOG2E, f0.w * SCALE_LOG2E),
                       pk2(f1.x * SCALE_LOG2E, f1.y * SCALE_LOG2E),
                       pk2(f1.z * SCALE_LOG2E, f1.w * SCALE_LOG2E)};
            aq[nt][kd] = __builtin_bit_cast(bf16x8, u);
        }
    }
}

// ============ cooperative fused kernel: attn partials + grid.sync + combine ==
// Attn body is the PROVEN R6/R8 attn_partial2, byte-identical. Grid 16x16x2 =
// 512 blocks = exactly 2 blocks/CU x 256 CU (co-residency guaranteed). After
// the partial-store epilogue: threadfence + grid sync, then each block
// normalizes 128 consecutive output rows (Opart still L2-warm).
__global__ __launch_bounds__(512, 4) void attn_combine_coop(
    const float* __restrict__ Q, const unsigned short* __restrict__ KV,
    const unsigned long long* __restrict__ pm,
    float* __restrict__ Opart, float* __restrict__ Lpart,
    float* __restrict__ O) {
    __shared__ __align__(16) unsigned short lk[2][64 * 64];
    __shared__ __align__(16) unsigned short lv[2][64 * 64];
    __shared__ __align__(16) unsigned short lpbuf[8][32 * 64];   // 4 KB per wave
    const int tid = threadIdx.x;
    const int lane = tid & 63;
    const int w = tid >> 6;
    const int n16 = lane & 15;
    const int quad = lane >> 4;
    const int bh = blockIdx.y;
    const int half = blockIdx.z;
    const int q0w = blockIdx.x * 256 + w * 32;
    unsigned short* lp = lpbuf[w];
    const unsigned short* kvb = KV + (size_t)bh * (64 * 8192) + (size_t)(half * 32) * 8192;

    bf16x8 aq[2][2];
    load_q_frags(Q, bh, q0w, n16, quad, aq);

    f32x4 oacc[4][2];
    f32x4 oaccl[2];
    const f32x4 z = {0.f, 0.f, 0.f, 0.f};
#pragma unroll
    for (int md = 0; md < 4; ++md)
#pragma unroll
        for (int nt = 0; nt < 2; ++nt) oacc[md][nt] = z;
    oaccl[0] = z;
    oaccl[1] = z;

    stage_tile8(kvb, lk[0], lv[0], tid);
    unsigned long long mrow_cur[2], mrow_nxt[2];
#pragma unroll
    for (int nt = 0; nt < 2; ++nt)
        mrow_cur[nt] = pm[(size_t)(half * 32) * S_LEN + q0w + nt * 16 + n16];

    for (int ktl = 0; ktl < 32; ++ktl) {
        const int cur = ktl & 1;
        const int ktn = (ktl + 1) & 31;
        __syncthreads();   // vmcnt(0) drain -> buf[cur] staged & everyone done with buf[!cur]
        stage_tile8(kvb + (size_t)ktn * 8192,
                    cur ? lk[0] : lk[1], cur ? lv[0] : lv[1], tid);
#pragma unroll
        for (int nt = 0; nt < 2; ++nt)
            mrow_nxt[nt] = pm[(size_t)(half * 32 + ktn) * S_LEN + q0w + nt * 16 + n16];
        compute_tile<1>(half * 32 + ktl, q0w, n16, quad, mrow_cur, nullptr, 1,
                        cur ? lk[1] : lk[0], cur ? lv[1] : lv[0], lp, aq, oacc, oaccl);
        mrow_cur[0] = mrow_nxt[0];
        mrow_cur[1] = mrow_nxt[1];
    }

    // store raw partial O^T (no normalization) + row sums (all lanes identical)
#pragma unroll
    for (int nt = 0; nt < 2; ++nt) {
        int q = q0w + nt * 16 + n16;
        if (quad == 0) Lpart[((size_t)(half * 16 + bh) << 12) + q] = oaccl[nt][0];
#pragma unroll
        for (int md = 0; md < 4; ++md) {
            float4 o;
            o.x = oacc[md][nt][0];
            o.y = oacc[md][nt][1];
            o.z = oacc[md][nt][2];
            o.w = oacc[md][nt][3];
            *(float4*)(Opart + (((size_t)(half * 16 + bh) << 12) + q) * 64 +
                       md * 16 + quad * 4) = o;
        }
    }

    // ---- grid-wide barrier, then fused combine (Opart still L2-warm) -------
    __threadfence();
    cooperative_groups::this_grid().sync();
    const int flat = (int)(blockIdx.x + gridDim.x * (blockIdx.y + gridDim.y * blockIdx.z));
#pragma unroll
    for (int i = 0; i < 4; ++i) {
        const int row = flat * 128 + i * 32 + (tid >> 4);   // bh*4096+q, 128 rows/block
        const int d4 = (tid & 15) * 4;
        const float* p0 = Opart + (size_t)row * 64 + d4;
        const float* p1 = p0 + (size_t)16 * S_LEN * 64;
        float4 a = *(const float4*)p0;
        float4 b = *(const float4*)p1;
        float l = Lpart[row] + Lpart[16 * S_LEN + row];
        float r = (l > 0.f) ? (1.0f / l) : 0.0f;
        float4 o;
        o.x = (a.x + b.x) * r;
        o.y = (a.y + b.y) * r;
        o.z = (a.z + b.z) * r;
        o.w = (a.w + b.w) * r;
        *(float4*)(O + (size_t)row * 64 + d4) = o;
    }
}

// ============ K-split kernel v3 (PROVEN R6/R8, non-coop fallback) ============
__global__ __launch_bounds__(512, 4) void attn_partial2(
    const float* __restrict__ Q, const unsigned short* __restrict__ KV,
    const unsigned long long* __restrict__ pm,
    float* __restrict__ Opart, float* __restrict__ Lpart) {
    __shared__ __align__(16) unsigned short lk[2][64 * 64];
    __shared__ __align__(16) unsigned short lv[2][64 * 64];
    __shared__ __align__(16) unsigned short lpbuf[8][32 * 64];   // 4 KB per wave
    const int tid = threadIdx.x;
    const int lane = tid & 63;
    const int w = tid >> 6;
    const int n16 = lane & 15;
    const int quad = lane >> 4;
    const int bh = blockIdx.y;
    const int half = blockIdx.z;
    const int q0w = blockIdx.x * 256 + w * 32;
    unsigned short* lp = lpbuf[w];
    const unsigned short* kvb = KV + (size_t)bh * (64 * 8192) + (size_t)(half * 32) * 8192;

    bf16x8 aq[2][2];
    load_q_frags(Q, bh, q0w, n16, quad, aq);

    f32x4 oacc[4][2];
    f32x4 oaccl[2];
    const f32x4 z = {0.f, 0.f, 0.f, 0.f};
#pragma unroll
    for (int md = 0; md < 4; ++md)
#pragma unroll
        for (int nt = 0; nt < 2; ++nt) oacc[md][nt] = z;
    oaccl[0] = z;
    oaccl[1] = z;

    stage_tile8(kvb, lk[0], lv[0], tid);
    unsigned long long mrow_cur[2], mrow_nxt[2];
#pragma unroll
    for (int nt = 0; nt < 2; ++nt)
        mrow_cur[nt] = pm[(size_t)(half * 32) * S_LEN + q0w + nt * 16 + n16];

    for (int ktl = 0; ktl < 32; ++ktl) {
        const int cur = ktl & 1;
        const int ktn = (ktl + 1) & 31;
        __syncthreads();
        stage_tile8(kvb + (size_t)ktn * 8192,
                    cur ? lk[0] : lk[1], cur ? lv[0] : lv[1], tid);
#pragma unroll
        for (int nt = 0; nt < 2; ++nt)
            mrow_nxt[nt] = pm[(size_t)(half * 32 + ktn) * S_LEN + q0w + nt * 16 + n16];
        compute_tile<1>(half * 32 + ktl, q0w, n16, quad, mrow_cur, nullptr, 1,
                        cur ? lk[1] : lk[0], cur ? lv[1] : lv[0], lp, aq, oacc, oaccl);
        mrow_cur[0] = mrow_nxt[0];
        mrow_cur[1] = mrow_nxt[1];
    }

#pragma unroll
    for (int nt = 0; nt < 2; ++nt) {
        int q = q0w + nt * 16 + n16;
        if (quad == 0) Lpart[((size_t)(half * 16 + bh) << 12) + q] = oaccl[nt][0];
#pragma unroll
        for (int md = 0; md < 4; ++md) {
            float4 o;
            o.x = oacc[md][nt][0];
            o.y = oacc[md][nt][1];
            o.z = oacc[md][nt][2];
            o.w = oacc[md][nt][3];
            *(float4*)(Opart + (((size_t)(half * 16 + bh) << 12) + q) * 64 +
                       md * 16 + quad * 4) = o;
        }
    }
}

// ============ K-split partial kernel (fallback, reg staging) =================
__global__ __launch_bounds__(256, 3) void attn_partial(
    const float* __restrict__ Q, const float* __restrict__ K, const float* __restrict__ V,
    const unsigned long long* __restrict__ pm,
    float* __restrict__ Opart, float* __restrict__ Lpart) {
    __shared__ __align__(16) unsigned short lk[2][64 * 64];
    __shared__ __align__(16) unsigned short lv[2][64 * 64];
    __shared__ __align__(16) unsigned short lpbuf[4][32 * 64];
    const int tid = threadIdx.x;
    const int lane = tid & 63;
    const int w = tid >> 6;
    const int n16 = lane & 15;
    const int quad = lane >> 4;
    const int bh = blockIdx.y;
    const int half = blockIdx.z;
    const int q0w = blockIdx.x * 128 + w * 32;
    const int kbase = half * 2048;
    unsigned short* lp = lpbuf[w];

    bf16x8 aq[2][2];
    load_q_frags(Q, bh, q0w, n16, quad, aq);

    f32x4 oacc[4][2];
    f32x4 oaccl[2];
    const f32x4 z = {0.f, 0.f, 0.f, 0.f};
#pragma unroll
    for (int md = 0; md < 4; ++md)
#pragma unroll
        for (int nt = 0; nt < 2; ++nt) oacc[md][nt] = z;
    oaccl[0] = z;
    oaccl[1] = z;

    unsigned kb[8], vb[8];
    pf_load(K, V, bh, kbase, tid, kb, vb);
    pf_store(tid, kb, vb, lk[0], lv[0]);
    unsigned long long mrow_cur[2], mrow_nxt[2];
#pragma unroll
    for (int nt = 0; nt < 2; ++nt)
        mrow_cur[nt] = pm[(size_t)(half * 32) * S_LEN + q0w + nt * 16 + n16];

    for (int ktl = 0; ktl < 32; ++ktl) {
        const int cur = ktl & 1;
        const int ktn = (ktl + 1) & 31;
        __syncthreads();
        pf_load(K, V, bh, kbase + ktn * 64, tid, kb, vb);
#pragma unroll
        for (int nt = 0; nt < 2; ++nt)
            mrow_nxt[nt] = pm[(size_t)(half * 32 + ktn) * S_LEN + q0w + nt * 16 + n16];
        compute_tile<1>(half * 32 + ktl, q0w, n16, quad, mrow_cur, nullptr, 1,
                        cur ? lk[1] : lk[0], cur ? lv[1] : lv[0], lp, aq, oacc, oaccl);
        pf_store(tid, kb, vb, cur ? lk[0] : lk[1], cur ? lv[0] : lv[1]);
        mrow_cur[0] = mrow_nxt[0];
        mrow_cur[1] = mrow_nxt[1];
    }

#pragma unroll
    for (int nt = 0; nt < 2; ++nt) {
        int q = q0w + nt * 16 + n16;
        if (quad == 0) Lpart[((size_t)(half * 16 + bh) << 12) + q] = oaccl[nt][0];
#pragma unroll
        for (int md = 0; md < 4; ++md) {
            float4 o;
            o.x = oacc[md][nt][0];
            o.y = oacc[md][nt][1];
            o.z = oacc[md][nt][2];
            o.w = oacc[md][nt][3];
            *(float4*)(Opart + (((size_t)(half * 16 + bh) << 12) + q) * 64 +
                       md * 16 + quad * 4) = o;
        }
    }
}

// ============ combine: O = (O0 + O1) / (l0 + l1) (non-coop fallback) =========
__global__ __launch_bounds__(256) void combine_kernel(
    const float* __restrict__ Opart, const float* __restrict__ Lpart,
    float* __restrict__ O) {
    for (int bx = blockIdx.x; bx < 16 * S_LEN / 16; bx += gridDim.x) {
        const int row = bx * 16 + (threadIdx.x >> 4);      // bh*4096+q
        const int d4 = (threadIdx.x & 15) * 4;
        const float* p0 = Opart + (size_t)row * 64 + d4;
        const float* p1 = p0 + (size_t)16 * S_LEN * 64;
        float4 a = *(const float4*)p0;
        float4 b = *(const float4*)p1;
        float l = Lpart[row] + Lpart[16 * S_LEN + row];
        float r = (l > 0.f) ? (1.0f / l) : 0.0f;
        float4 o;
        o.x = (a.x + b.x) * r;
        o.y = (a.y + b.y) * r;
        o.z = (a.z + b.z) * r;
        o.w = (a.w + b.w) * r;
        *(float4*)(O + (size_t)row * 64 + d4) = o;
    }
}

// ============ fallback: single kernel, full key range ========================
template <int USE_PACKED>
__global__ __launch_bounds__(256, 3) void attn_kernel(
    const float* __restrict__ Q, const float* __restrict__ K, const float* __restrict__ V,
    const unsigned long long* __restrict__ pm, const unsigned* __restrict__ rawmask,
    float* __restrict__ O) {
    __shared__ __align__(16) unsigned short lk[2][64 * 64];
    __shared__ __align__(16) unsigned short lv[2][64 * 64];
    __shared__ __align__(16) unsigned short lpbuf[4][32 * 64];
    const int tid = threadIdx.x;
    const int lane = tid & 63;
    const int w = tid >> 6;
    const int n16 = lane & 15;
    const int quad = lane >> 4;
    const int bh = blockIdx.y;
    const int q0w = blockIdx.x * 128 + w * 32;
    unsigned short* lp = lpbuf[w];

    int mask_is_word = 1;
    if (!USE_PACKED) {
        unsigned v = rawmask[lane];
        bool okw = (v == 0u) || (v == 1u) || (v == 0x3F800000u);
        mask_is_word = (__ballot(okw) == ~0ull) ? 1 : 0;
    }

    bf16x8 aq[2][2];
    load_q_frags(Q, bh, q0w, n16, quad, aq);

    f32x4 oacc[4][2];
    f32x4 oaccl[2];
    const f32x4 z = {0.f, 0.f, 0.f, 0.f};
#pragma unroll
    for (int md = 0; md < 4; ++md)
#pragma unroll
        for (int nt = 0; nt < 2; ++nt) oacc[md][nt] = z;
    oaccl[0] = z;
    oaccl[1] = z;

    unsigned kb[8], vb[8];
    pf_load(K, V, bh, 0, tid, kb, vb);
    pf_store(tid, kb, vb, lk[0], lv[0]);
    unsigned long long mrow_cur[2] = {0, 0}, mrow_nxt[2] = {0, 0};
    if (USE_PACKED) {
#pragma unroll
        for (int nt = 0; nt < 2; ++nt)
            mrow_cur[nt] = pm[(size_t)0 * S_LEN + q0w + nt * 16 + n16];
    }

    for (int kt = 0; kt < 64; ++kt) {
        const int cur = kt & 1;
        const int ktn = (kt + 1) & 63;
        __syncthreads();
        pf_load(K, V, bh, ktn * 64, tid, kb, vb);
        if (USE_PACKED) {
#pragma unroll
            for (int nt = 0; nt < 2; ++nt)
                mrow_nxt[nt] = pm[(size_t)ktn * S_LEN + q0w + nt * 16 + n16];
        }
        compute_tile<USE_PACKED>(kt, q0w, n16, quad, mrow_cur, rawmask, mask_is_word,
                                 cur ? lk[1] : lk[0], cur ? lv[1] : lv[0], lp, aq, oacc,
                                 oaccl);
        pf_store(tid, kb, vb, cur ? lk[0] : lk[1], cur ? lv[0] : lv[1]);
        mrow_cur[0] = mrow_nxt[0];
        mrow_cur[1] = mrow_nxt[1];
    }

    float rcpl[2];
#pragma unroll
    for (int nt = 0; nt < 2; ++nt) {
        float l = oaccl[nt][0];
        rcpl[nt] = (l > 0.f) ? (1.0f / l) : 0.0f;
    }
#pragma unroll
    for (int md = 0; md < 4; ++md)
#pragma unroll
        for (int nt = 0; nt < 2; ++nt) {
            int q = q0w + nt * 16 + n16;
            float4 o;
            o.x = oacc[md][nt][0] * rcpl[nt];
            o.y = oacc[md][nt][1] * rcpl[nt];
            o.z = oacc[md][nt][2] * rcpl[nt];
            o.w = oacc[md][nt][3] * rcpl[nt];
            *(float4*)(O + ((size_t)(bh * S_LEN + q) << 6) + md * 16 + quad * 4) = o;
        }
}

extern "C" void kernel_launch(void* const* d_in, const int* in_sizes, int n_in,
                              void* d_out, int out_size, void* d_ws, size_t ws_size,
                              hipStream_t stream) {
    (void)in_sizes; (void)n_in; (void)out_size;
    const float* Q = (const float*)d_in[0];
    const float* K = (const float*)d_in[1];
    const float* V = (const float*)d_in[2];
    const void* mask = d_in[4];
    float* O = (float*)d_out;

    const size_t bitfield_bytes = (size_t)S_LEN * S_LEN / 8;       // 2 MB
    const size_t opart_bytes = (size_t)2 * 16 * S_LEN * 64 * 4;    // 33.55 MB
    const size_t lpart_bytes = (size_t)2 * 16 * S_LEN * 4;         // 0.52 MB
    const size_t kv_bytes = (size_t)16 * S_LEN * 64 * 2 * 2;       // 16.78 MB
    const size_t need_packed = 1024 + bitfield_bytes;
    const size_t need_split = need_packed + opart_bytes + lpart_bytes;
    const size_t need_full = need_split + kv_bytes;

    unsigned long long* pmw = (unsigned long long*)((char*)d_ws + 1024);
    float* opart = (float*)((char*)d_ws + need_packed);
    float* lpart = opart + (size_t)2 * 16 * S_LEN * 64;
    unsigned short* kvp = (unsigned short*)((char*)d_ws + need_split);

    if (d_ws != nullptr && ws_size >= need_full) {
        pack_mask_kernel<<<dim3(2048), 256, 0, stream>>>((const unsigned*)mask, pmw);
        kv_convert_kernel<<<dim3(64, 16), 256, 0, stream>>>(K, V, kvp);
        const unsigned short* kvc = kvp;
        const unsigned long long* pmc = pmw;
        void* args[] = {(void*)&Q, (void*)&kvc, (void*)&pmc,
                        (void*)&opart, (void*)&lpart, (void*)&O};
        hipError_t ce = hipLaunchCooperativeKernel(
            (const void*)attn_combine_coop, dim3(S_LEN / 256, 16, 2), dim3(512),
            args, 0, stream);
        if (ce != hipSuccess) {   // coop unsupported -> proven separate path
            attn_partial2<<<dim3(S_LEN / 256, 16, 2), 512, 0, stream>>>(
                Q, kvp, pmw, opart, lpart);
            combine_kernel<<<dim3(1024), 256, 0, stream>>>(opart, lpart, O);
        }
    } else if (d_ws != nullptr && ws_size >= need_split) {
        pack_mask_kernel<<<dim3(2048), 256, 0, stream>>>((const unsigned*)mask, pmw);
        attn_partial<<<dim3(S_LEN / 128, 16, 2), 256, 0, stream>>>(
            Q, K, V, pmw, opart, lpart);
        combine_kernel<<<dim3(1024), 256, 0, stream>>>(opart, lpart, O);
    } else if (d_ws != nullptr && ws_size >= need_packed) {
        pack_mask_kernel<<<dim3(2048), 256, 0, stream>>>((const unsigned*)mask, pmw);
        attn_kernel<1><<<dim3(S_LEN / 128, 16), 256, 0, stream>>>(
            Q, K, V, pmw, (const unsigned*)mask, O);
    } else {
        attn_kernel<0><<<dim3(S_LEN / 128, 16), 256, 0, stream>>>(
            Q, K, V, nullptr, (const unsigned*)mask, O);
    }
}

// Round 10
// 240.353 us; speedup vs baseline: 1.8790x; 1.8790x over previous
//
#include <hip/hip_runtime.h>
#include <stdint.h>

#define S_LEN 4096
#define SCALE_LOG2E 0.18033688011112042f   // (1/sqrt(64)) * log2(e), folded into Q

typedef __attribute__((ext_vector_type(8))) short bf16x8;
typedef __attribute__((ext_vector_type(4))) float f32x4;

#if __has_builtin(__builtin_amdgcn_exp2f)
#define EXP2(x) __builtin_amdgcn_exp2f(x)
#else
#define EXP2(x) exp2f(x)
#endif

#if __has_builtin(__builtin_amdgcn_sbfe)
#define SBFE1(x, o) __builtin_amdgcn_sbfe((int)(x), (o), 1)
#else
#define SBFE1(x, o) (((int)((unsigned)(x) << (31 - (o)))) >> 31)
#endif

__device__ __forceinline__ unsigned pk2(float a, float b) {
    // round-half-up bf16 pair pack: +0x8000 then take high halves via v_perm
    unsigned ua = __builtin_bit_cast(unsigned, a) + 0x8000u;
    unsigned ub = __builtin_bit_cast(unsigned, b) + 0x8000u;
    return __builtin_amdgcn_perm(ub, ua, 0x07060302u);
}

// packed f32->bf16 pair (lo = a, hi = b), single instruction
__device__ __forceinline__ unsigned cvtpk(float a, float b) {
    unsigned r;
    asm("v_cvt_pk_bf16_f32 %0, %1, %2" : "=v"(r) : "v"(a), "v"(b));
    return r;
}

__device__ __forceinline__ f32x4 mfma16(bf16x8 a, bf16x8 b, f32x4 c) {
    return __builtin_amdgcn_mfma_f32_16x16x32_bf16(a, b, c, 0, 0, 0);
}

__device__ __forceinline__ bf16x8 bf16_ones() {
    uint4 q = {0x3F803F80u, 0x3F803F80u, 0x3F803F80u, 0x3F803F80u};
    return __builtin_bit_cast(bf16x8, q);
}

// async 16B global->LDS copy (LDS dest = wave-uniform base + lane*16)
__device__ __forceinline__ void gld16(const void* g, void* l) {
    __builtin_amdgcn_global_load_lds(
        (const __attribute__((address_space(1))) unsigned*)g,
        (__attribute__((address_space(3))) unsigned*)l, 16, 0, 0);
}

// ---------------- staging: global fp32 -> regs (packed bf16), 256 threads ----
__device__ __forceinline__ void pf_load(const float* __restrict__ K,
                                        const float* __restrict__ V,
                                        int bh, int k0, int t,
                                        unsigned* kb, unsigned* vb) {
    const int r = t >> 2, h = t & 3;
    const float* kp = K + (((size_t)(bh * S_LEN + k0 + r)) << 6) + h * 16;
#pragma unroll
    for (int cc = 0; cc < 2; ++cc) {
        float4 f0 = ((const float4*)kp)[cc * 2];
        float4 f1 = ((const float4*)kp)[cc * 2 + 1];
        kb[cc * 4 + 0] = pk2(f0.x, f0.y);
        kb[cc * 4 + 1] = pk2(f0.z, f0.w);
        kb[cc * 4 + 2] = pk2(f1.x, f1.y);
        kb[cc * 4 + 3] = pk2(f1.z, f1.w);
    }
    const int d = t & 63, g = t >> 6;
    const float* vp = V + (((size_t)(bh * S_LEN + k0 + g * 16)) << 6) + d;
#pragma unroll
    for (int c8 = 0; c8 < 2; ++c8) {
        float f[8];
#pragma unroll
        for (int i = 0; i < 8; ++i) f[i] = vp[(c8 * 8 + i) * 64];
        vb[c8 * 4 + 0] = pk2(f[0], f[1]);
        vb[c8 * 4 + 1] = pk2(f[2], f[3]);
        vb[c8 * 4 + 2] = pk2(f[4], f[5]);
        vb[c8 * 4 + 3] = pk2(f[6], f[7]);
    }
}

__device__ __forceinline__ void pf_store(int t, const unsigned* kb, const unsigned* vb,
                                         unsigned short* lk, unsigned short* lv) {
    const int r = t >> 2, h = t & 3;
#pragma unroll
    for (int cc = 0; cc < 2; ++cc) {
        int c = h * 2 + cc;
        uint4 st = {kb[cc * 4 + 0], kb[cc * 4 + 1], kb[cc * 4 + 2], kb[cc * 4 + 3]};
        *(uint4*)&lk[r * 64 + ((c ^ (r & 7)) << 3)] = st;
    }
    const int d = t & 63, g = t >> 6;
#pragma unroll
    for (int c8 = 0; c8 < 2; ++c8) {
        int c = g * 2 + c8;
        uint4 st = {vb[c8 * 4 + 0], vb[c8 * 4 + 1], vb[c8 * 4 + 2], vb[c8 * 4 + 3]};
        *(uint4*)&lv[d * 64 + ((c ^ (d & 7)) << 3)] = st;
    }
}

// ------ fused pre-pass: mask bitfield pack + fp32 K/V -> bf16 swizzled tiles -
// pack_mask and kv_convert are independent and each runs at ~2 TB/s (latency-
// limited, not HBM-saturated) -> fuse so they overlap and one launch is saved.
// Blocks [0,1024) convert one (bh,kt) KV tile (byte-identical kv_convert body);
// ALL 2048 blocks grid-stride the mask pack over 16384 logical blocks
// (byte-identical R8 pack_mask body).
__global__ __launch_bounds__(256) void prep_kernel(
    const unsigned* __restrict__ m32, unsigned long long* __restrict__ out,
    const float* __restrict__ K, const float* __restrict__ V,
    unsigned short* __restrict__ kv) {
    const int t = threadIdx.x;
    if (blockIdx.x < 1024) {            // kv convert: tile kt of head bh
        const int kt = blockIdx.x & 63;
        const int bh = blockIdx.x >> 6;
        unsigned kb[8], vb[8];
        pf_load(K, V, bh, kt * 64, t, kb, vb);
        unsigned short* base = kv + ((size_t)(bh * 64 + kt)) * 8192;   // 16 KB/tile
        pf_store(t, kb, vb, base, base + 4096);
    }
    // mask packing: bool(any encoding) -> bitfield, [kt][q] layout
    const int lane = t & 63;
    const int w = t >> 6;
    unsigned pv = m32[lane];
    bool okw = (pv == 0u) || (pv == 1u) || (pv == 0x3F800000u);
    const bool is_word = (__ballot(okw) == ~0ull);
    const unsigned char* m8 = (const unsigned char*)m32;
    for (int bx = blockIdx.x; bx < 16384; bx += gridDim.x) {
        const long long wbase = ((long long)bx * 4 + w) * 4;   // u64 words (q*64+kt)
#pragma unroll
        for (int it = 0; it < 4; ++it) {
            const long long word = wbase + it;
            long long e = word * 64 + lane;
            bool bit = is_word ? (m32[e] != 0u) : (m8[e] != 0);
            unsigned long long bal = __ballot(bit);
            if (lane == 0) {
                long long q = word >> 6, kt = word & 63;
                out[kt * S_LEN + q] = bal;   // transposed: coalesced reads in attn
            }
        }
    }
}

// standalone mask packer (fallback paths without KV workspace)
__global__ __launch_bounds__(256) void pack_mask_kernel(
    const unsigned* __restrict__ m32, unsigned long long* __restrict__ out) {
    const int lane = threadIdx.x & 63;
    const int w = threadIdx.x >> 6;
    unsigned pv = m32[lane];
    bool okw = (pv == 0u) || (pv == 1u) || (pv == 0x3F800000u);
    const bool is_word = (__ballot(okw) == ~0ull);
    const unsigned char* m8 = (const unsigned char*)m32;
    for (int bx = blockIdx.x; bx < 16384; bx += gridDim.x) {
        const long long wbase = ((long long)bx * 4 + w) * 4;
#pragma unroll
        for (int it = 0; it < 4; ++it) {
            const long long word = wbase + it;
            long long e = word * 64 + lane;
            bool bit = is_word ? (m32[e] != 0u) : (m8[e] != 0);
            unsigned long long bal = __ballot(bit);
            if (lane == 0) {
                long long q = word >> 6, kt = word & 63;
                out[kt * S_LEN + q] = bal;
            }
        }
    }
}

// async-stage one prepacked 16 KB tile with 8 waves: 2 x gld16 per thread
__device__ __forceinline__ void stage_tile8(const unsigned short* kvtile,
                                            unsigned short* lk, unsigned short* lv,
                                            int tid) {
    const int w = tid >> 6;
    const int lane = tid & 63;
    const char* g = (const char*)kvtile + w * 1024 + lane * 16;
    gld16(g, (char*)lk + w * 1024);            // K half: bytes [0, 8K)
    gld16(g + 8192, (char*)lv + w * 1024);     // V half: bytes [8K, 16K)
}

// ---------------- one 64-key tile: S^T = K·Q^T, softmax, O^T += V^T·P^T ------
// PROVEN R2/R6/R8 STRUCTURE (byte-identical).
template <int USE_PACKED>
__device__ __forceinline__ void compute_tile(
    int kt, int q0w, int n16, int quad,
    const unsigned long long (&mrow)[2],
    const unsigned* __restrict__ rawmask, int mask_is_word,
    const unsigned short* lk, const unsigned short* lv, unsigned short* lp,
    const bf16x8 (&aq)[2][2], f32x4 (&oacc)[4][2], f32x4 (&oaccl)[2]) {
    const int k0 = kt * 64;
    const f32x4 z = {0.f, 0.f, 0.f, 0.f};
    unsigned nmw[2][2];
    if (USE_PACKED) {
#pragma unroll
        for (int nt = 0; nt < 2; ++nt) {
            unsigned long long nm = ~(mrow[nt] >> (quad * 4));
            nmw[nt][0] = (unsigned)nm;
            nmw[nt][1] = (unsigned)(nm >> 32);
        }
    }
#pragma unroll
    for (int mth = 0; mth < 2; ++mth) {
        f32x4 sac[2][2];
#pragma unroll
        for (int mi = 0; mi < 2; ++mi)
#pragma unroll
            for (int nt = 0; nt < 2; ++nt) {
                if (USE_PACKED) {
                    const int mt = mth * 2 + mi;
#pragma unroll
                    for (int reg = 0; reg < 4; ++reg) {
                        unsigned ext = (unsigned)SBFE1(nmw[nt][mt >> 1], (mt & 1) * 16 + reg);
                        sac[mi][nt][reg] = __builtin_bit_cast(float, 0xFF800000u & ext);
                    }
                } else {
                    sac[mi][nt] = z;
                }
            }
        __builtin_amdgcn_s_setprio(1);
#pragma unroll
        for (int kd = 0; kd < 2; ++kd) {
#pragma unroll
            for (int mi = 0; mi < 2; ++mi) {
                int row = (mth * 2 + mi) * 16 + n16;
                bf16x8 ak = *(const bf16x8*)&lk[row * 64 + (((kd * 4 + quad) ^ (row & 7)) << 3)];
#pragma unroll
                for (int nt = 0; nt < 2; ++nt)
                    sac[mi][nt] = mfma16(ak, aq[nt][kd], sac[mi][nt]);
            }
        }
        __builtin_amdgcn_s_setprio(0);
#pragma unroll
        for (int mi = 0; mi < 2; ++mi) {
#pragma unroll
            for (int nt = 0; nt < 2; ++nt) {
                const int mt = mth * 2 + mi;
                float p[4];
#pragma unroll
                for (int reg = 0; reg < 4; ++reg) {
                    float e = EXP2(sac[mi][nt][reg]);
                    if (!USE_PACKED) {
                        int pos = mt * 16 + quad * 4 + reg;
                        size_t mi2 = (size_t)(q0w + nt * 16 + n16) * S_LEN + k0 + pos;
                        bool bit = mask_is_word ? (rawmask[mi2] != 0u)
                                                : (((const unsigned char*)rawmask)[mi2] != 0);
                        e = bit ? e : 0.0f;
                    }
                    p[reg] = e;
                }
                uint2 pr = {cvtpk(p[0], p[1]), cvtpk(p[2], p[3])};
                const int r = nt * 16 + n16;
                const int chunk = (mt * 2 + (quad >> 1)) ^ (n16 & 7);
                *(uint2*)((char*)lp + r * 128 + chunk * 16 + (quad & 1) * 8) = pr;
            }
        }
    }
    const bf16x8 onesv = bf16_ones();
    __builtin_amdgcn_s_setprio(1);
#pragma unroll
    for (int kk = 0; kk < 2; ++kk) {
        bf16x8 av[4];
#pragma unroll
        for (int md = 0; md < 4; ++md) {
            int dr = md * 16 + n16;
            av[md] = *(const bf16x8*)&lv[dr * 64 + (((kk * 4 + quad) ^ (dr & 7)) << 3)];
        }
#pragma unroll
        for (int nt = 0; nt < 2; ++nt) {
            const int r = nt * 16 + n16;
            const int chunk = (kk * 4 + quad) ^ (n16 & 7);
            bf16x8 pb = *(const bf16x8*)((const char*)lp + r * 128 + chunk * 16);
#pragma unroll
            for (int md = 0; md < 4; ++md)
                oacc[md][nt] = mfma16(av[md], pb, oacc[md][nt]);
            oaccl[nt] = mfma16(onesv, pb, oaccl[nt]);   // row sums on MFMA pipe
        }
    }
    __builtin_amdgcn_s_setprio(0);
}

__device__ __forceinline__ void load_q_frags(const float* __restrict__ Q, int bh, int q0w,
                                             int n16, int quad, bf16x8 (&aq)[2][2]) {
#pragma unroll
    for (int nt = 0; nt < 2; ++nt) {
        const float* qp = Q + ((size_t)(bh * S_LEN + q0w + nt * 16 + n16) << 6);
#pragma unroll
        for (int kd = 0; kd < 2; ++kd) {
            float4 f0 = *(const float4*)(qp + kd * 32 + quad * 8);
            float4 f1 = *(const float4*)(qp + kd * 32 + quad * 8 + 4);
            uint4 u = {pk2(f0.x * SCALE_LOG2E, f0.y * SCALE_LOG2E),
                       pk2(f0.z * SCALE_LOG2E, f0.w * SCALE_LOG2E),
                       pk2(f1.x * SCALE_LOG2E, f1.y * SCALE_LOG2E),
                       pk2(f1.z * SCALE_LOG2E, f1.w * SCALE_LOG2E)};
            aq[nt][kd] = __builtin_bit_cast(bf16x8, u);
        }
    }
}

// ============ K-split kernel v3 (PROVEN R6/R8): 512 threads, shared KV dbuf ==
// LDS = 16 (lk) + 16 (lv) + 8x4 (lp) = 64 KB -> 2 blocks/CU = 16 waves/CU
// = 4 waves/SIMD. Grid 16x16x2 = 512 = 2x256CU: whole grid resident, no tail.
__global__ __launch_bounds__(512, 4) void attn_partial2(
    const float* __restrict__ Q, const unsigned short* __restrict__ KV,
    const unsigned long long* __restrict__ pm,
    float* __restrict__ Opart, float* __restrict__ Lpart) {
    __shared__ __align__(16) unsigned short lk[2][64 * 64];
    __shared__ __align__(16) unsigned short lv[2][64 * 64];
    __shared__ __align__(16) unsigned short lpbuf[8][32 * 64];   // 4 KB per wave
    const int tid = threadIdx.x;
    const int lane = tid & 63;
    const int w = tid >> 6;
    const int n16 = lane & 15;
    const int quad = lane >> 4;
    const int bh = blockIdx.y;
    const int half = blockIdx.z;
    const int q0w = blockIdx.x * 256 + w * 32;
    unsigned short* lp = lpbuf[w];
    const unsigned short* kvb = KV + (size_t)bh * (64 * 8192) + (size_t)(half * 32) * 8192;

    bf16x8 aq[2][2];
    load_q_frags(Q, bh, q0w, n16, quad, aq);

    f32x4 oacc[4][2];
    f32x4 oaccl[2];
    const f32x4 z = {0.f, 0.f, 0.f, 0.f};
#pragma unroll
    for (int md = 0; md < 4; ++md)
#pragma unroll
        for (int nt = 0; nt < 2; ++nt) oacc[md][nt] = z;
    oaccl[0] = z;
    oaccl[1] = z;

    stage_tile8(kvb, lk[0], lv[0], tid);
    unsigned long long mrow_cur[2], mrow_nxt[2];
#pragma unroll
    for (int nt = 0; nt < 2; ++nt)
        mrow_cur[nt] = pm[(size_t)(half * 32) * S_LEN + q0w + nt * 16 + n16];

    for (int ktl = 0; ktl < 32; ++ktl) {
        const int cur = ktl & 1;
        const int ktn = (ktl + 1) & 31;
        __syncthreads();   // vmcnt(0) drain -> buf[cur] staged & everyone done with buf[!cur]
        stage_tile8(kvb + (size_t)ktn * 8192,
                    cur ? lk[0] : lk[1], cur ? lv[0] : lv[1], tid);
#pragma unroll
        for (int nt = 0; nt < 2; ++nt)
            mrow_nxt[nt] = pm[(size_t)(half * 32 + ktn) * S_LEN + q0w + nt * 16 + n16];
        compute_tile<1>(half * 32 + ktl, q0w, n16, quad, mrow_cur, nullptr, 1,
                        cur ? lk[1] : lk[0], cur ? lv[1] : lv[0], lp, aq, oacc, oaccl);
        mrow_cur[0] = mrow_nxt[0];
        mrow_cur[1] = mrow_nxt[1];
    }

    // store raw partial O^T (no normalization) + row sums (all lanes identical)
#pragma unroll
    for (int nt = 0; nt < 2; ++nt) {
        int q = q0w + nt * 16 + n16;
        if (quad == 0) Lpart[((size_t)(half * 16 + bh) << 12) + q] = oaccl[nt][0];
#pragma unroll
        for (int md = 0; md < 4; ++md) {
            float4 o;
            o.x = oacc[md][nt][0];
            o.y = oacc[md][nt][1];
            o.z = oacc[md][nt][2];
            o.w = oacc[md][nt][3];
            *(float4*)(Opart + (((size_t)(half * 16 + bh) << 12) + q) * 64 +
                       md * 16 + quad * 4) = o;
        }
    }
}

// ============ K-split partial kernel (fallback, reg staging) =================
__global__ __launch_bounds__(256, 3) void attn_partial(
    const float* __restrict__ Q, const float* __restrict__ K, const float* __restrict__ V,
    const unsigned long long* __restrict__ pm,
    float* __restrict__ Opart, float* __restrict__ Lpart) {
    __shared__ __align__(16) unsigned short lk[2][64 * 64];
    __shared__ __align__(16) unsigned short lv[2][64 * 64];
    __shared__ __align__(16) unsigned short lpbuf[4][32 * 64];
    const int tid = threadIdx.x;
    const int lane = tid & 63;
    const int w = tid >> 6;
    const int n16 = lane & 15;
    const int quad = lane >> 4;
    const int bh = blockIdx.y;
    const int half = blockIdx.z;
    const int q0w = blockIdx.x * 128 + w * 32;
    const int kbase = half * 2048;
    unsigned short* lp = lpbuf[w];

    bf16x8 aq[2][2];
    load_q_frags(Q, bh, q0w, n16, quad, aq);

    f32x4 oacc[4][2];
    f32x4 oaccl[2];
    const f32x4 z = {0.f, 0.f, 0.f, 0.f};
#pragma unroll
    for (int md = 0; md < 4; ++md)
#pragma unroll
        for (int nt = 0; nt < 2; ++nt) oacc[md][nt] = z;
    oaccl[0] = z;
    oaccl[1] = z;

    unsigned kb[8], vb[8];
    pf_load(K, V, bh, kbase, tid, kb, vb);
    pf_store(tid, kb, vb, lk[0], lv[0]);
    unsigned long long mrow_cur[2], mrow_nxt[2];
#pragma unroll
    for (int nt = 0; nt < 2; ++nt)
        mrow_cur[nt] = pm[(size_t)(half * 32) * S_LEN + q0w + nt * 16 + n16];

    for (int ktl = 0; ktl < 32; ++ktl) {
        const int cur = ktl & 1;
        const int ktn = (ktl + 1) & 31;
        __syncthreads();
        pf_load(K, V, bh, kbase + ktn * 64, tid, kb, vb);
#pragma unroll
        for (int nt = 0; nt < 2; ++nt)
            mrow_nxt[nt] = pm[(size_t)(half * 32 + ktn) * S_LEN + q0w + nt * 16 + n16];
        compute_tile<1>(half * 32 + ktl, q0w, n16, quad, mrow_cur, nullptr, 1,
                        cur ? lk[1] : lk[0], cur ? lv[1] : lv[0], lp, aq, oacc, oaccl);
        pf_store(tid, kb, vb, cur ? lk[0] : lk[1], cur ? lv[0] : lv[1]);
        mrow_cur[0] = mrow_nxt[0];
        mrow_cur[1] = mrow_nxt[1];
    }

#pragma unroll
    for (int nt = 0; nt < 2; ++nt) {
        int q = q0w + nt * 16 + n16;
        if (quad == 0) Lpart[((size_t)(half * 16 + bh) << 12) + q] = oaccl[nt][0];
#pragma unroll
        for (int md = 0; md < 4; ++md) {
            float4 o;
            o.x = oacc[md][nt][0];
            o.y = oacc[md][nt][1];
            o.z = oacc[md][nt][2];
            o.w = oacc[md][nt][3];
            *(float4*)(Opart + (((size_t)(half * 16 + bh) << 12) + q) * 64 +
                       md * 16 + quad * 4) = o;
        }
    }
}

// ============ combine: O = (O0 + O1) / (l0 + l1) =============================
// Grid-stride over 4096 logical blocks (1024 launched x 4).
__global__ __launch_bounds__(256) void combine_kernel(
    const float* __restrict__ Opart, const float* __restrict__ Lpart,
    float* __restrict__ O) {
    for (int bx = blockIdx.x; bx < 16 * S_LEN / 16; bx += gridDim.x) {
        const int row = bx * 16 + (threadIdx.x >> 4);      // bh*4096+q
        const int d4 = (threadIdx.x & 15) * 4;
        const float* p0 = Opart + (size_t)row * 64 + d4;
        const float* p1 = p0 + (size_t)16 * S_LEN * 64;
        float4 a = *(const float4*)p0;
        float4 b = *(const float4*)p1;
        float l = Lpart[row] + Lpart[16 * S_LEN + row];
        float r = (l > 0.f) ? (1.0f / l) : 0.0f;
        float4 o;
        o.x = (a.x + b.x) * r;
        o.y = (a.y + b.y) * r;
        o.z = (a.z + b.z) * r;
        o.w = (a.w + b.w) * r;
        *(float4*)(O + (size_t)row * 64 + d4) = o;
    }
}

// ============ fallback: single kernel, full key range ========================
template <int USE_PACKED>
__global__ __launch_bounds__(256, 3) void attn_kernel(
    const float* __restrict__ Q, const float* __restrict__ K, const float* __restrict__ V,
    const unsigned long long* __restrict__ pm, const unsigned* __restrict__ rawmask,
    float* __restrict__ O) {
    __shared__ __align__(16) unsigned short lk[2][64 * 64];
    __shared__ __align__(16) unsigned short lv[2][64 * 64];
    __shared__ __align__(16) unsigned short lpbuf[4][32 * 64];
    const int tid = threadIdx.x;
    const int lane = tid & 63;
    const int w = tid >> 6;
    const int n16 = lane & 15;
    const int quad = lane >> 4;
    const int bh = blockIdx.y;
    const int q0w = blockIdx.x * 128 + w * 32;
    unsigned short* lp = lpbuf[w];

    int mask_is_word = 1;
    if (!USE_PACKED) {
        unsigned v = rawmask[lane];
        bool okw = (v == 0u) || (v == 1u) || (v == 0x3F800000u);
        mask_is_word = (__ballot(okw) == ~0ull) ? 1 : 0;
    }

    bf16x8 aq[2][2];
    load_q_frags(Q, bh, q0w, n16, quad, aq);

    f32x4 oacc[4][2];
    f32x4 oaccl[2];
    const f32x4 z = {0.f, 0.f, 0.f, 0.f};
#pragma unroll
    for (int md = 0; md < 4; ++md)
#pragma unroll
        for (int nt = 0; nt < 2; ++nt) oacc[md][nt] = z;
    oaccl[0] = z;
    oaccl[1] = z;

    unsigned kb[8], vb[8];
    pf_load(K, V, bh, 0, tid, kb, vb);
    pf_store(tid, kb, vb, lk[0], lv[0]);
    unsigned long long mrow_cur[2] = {0, 0}, mrow_nxt[2] = {0, 0};
    if (USE_PACKED) {
#pragma unroll
        for (int nt = 0; nt < 2; ++nt)
            mrow_cur[nt] = pm[(size_t)0 * S_LEN + q0w + nt * 16 + n16];
    }

    for (int kt = 0; kt < 64; ++kt) {
        const int cur = kt & 1;
        const int ktn = (kt + 1) & 63;
        __syncthreads();
        pf_load(K, V, bh, ktn * 64, tid, kb, vb);
        if (USE_PACKED) {
#pragma unroll
            for (int nt = 0; nt < 2; ++nt)
                mrow_nxt[nt] = pm[(size_t)ktn * S_LEN + q0w + nt * 16 + n16];
        }
        compute_tile<USE_PACKED>(kt, q0w, n16, quad, mrow_cur, rawmask, mask_is_word,
                                 cur ? lk[1] : lk[0], cur ? lv[1] : lv[0], lp, aq, oacc,
                                 oaccl);
        pf_store(tid, kb, vb, cur ? lk[0] : lk[1], cur ? lv[0] : lv[1]);
        mrow_cur[0] = mrow_nxt[0];
        mrow_cur[1] = mrow_nxt[1];
    }

    float rcpl[2];
#pragma unroll
    for (int nt = 0; nt < 2; ++nt) {
        float l = oaccl[nt][0];
        rcpl[nt] = (l > 0.f) ? (1.0f / l) : 0.0f;
    }
#pragma unroll
    for (int md = 0; md < 4; ++md)
#pragma unroll
        for (int nt = 0; nt < 2; ++nt) {
            int q = q0w + nt * 16 + n16;
            float4 o;
            o.x = oacc[md][nt][0] * rcpl[nt];
            o.y = oacc[md][nt][1] * rcpl[nt];
            o.z = oacc[md][nt][2] * rcpl[nt];
            o.w = oacc[md][nt][3] * rcpl[nt];
            *(float4*)(O + ((size_t)(bh * S_LEN + q) << 6) + md * 16 + quad * 4) = o;
        }
}

extern "C" void kernel_launch(void* const* d_in, const int* in_sizes, int n_in,
                              void* d_out, int out_size, void* d_ws, size_t ws_size,
                              hipStream_t stream) {
    (void)in_sizes; (void)n_in; (void)out_size;
    const float* Q = (const float*)d_in[0];
    const float* K = (const float*)d_in[1];
    const float* V = (const float*)d_in[2];
    const void* mask = d_in[4];
    float* O = (float*)d_out;

    const size_t bitfield_bytes = (size_t)S_LEN * S_LEN / 8;       // 2 MB
    const size_t opart_bytes = (size_t)2 * 16 * S_LEN * 64 * 4;    // 33.55 MB
    const size_t lpart_bytes = (size_t)2 * 16 * S_LEN * 4;         // 0.52 MB
    const size_t kv_bytes = (size_t)16 * S_LEN * 64 * 2 * 2;       // 16.78 MB
    const size_t need_packed = 1024 + bitfield_bytes;
    const size_t need_split = need_packed + opart_bytes + lpart_bytes;
    const size_t need_full = need_split + kv_bytes;

    unsigned long long* pmw = (unsigned long long*)((char*)d_ws + 1024);
    float* opart = (float*)((char*)d_ws + need_packed);
    float* lpart = opart + (size_t)2 * 16 * S_LEN * 64;
    unsigned short* kvp = (unsigned short*)((char*)d_ws + need_split);

    if (d_ws != nullptr && ws_size >= need_full) {
        prep_kernel<<<dim3(2048), 256, 0, stream>>>(
            (const unsigned*)mask, pmw, K, V, kvp);
        attn_partial2<<<dim3(S_LEN / 256, 16, 2), 512, 0, stream>>>(
            Q, kvp, pmw, opart, lpart);
        combine_kernel<<<dim3(1024), 256, 0, stream>>>(opart, lpart, O);
    } else if (d_ws != nullptr && ws_size >= need_split) {
        pack_mask_kernel<<<dim3(2048), 256, 0, stream>>>((const unsigned*)mask, pmw);
        attn_partial<<<dim3(S_LEN / 128, 16, 2), 256, 0, stream>>>(
            Q, K, V, pmw, opart, lpart);
        combine_kernel<<<dim3(1024), 256, 0, stream>>>(opart, lpart, O);
    } else if (d_ws != nullptr && ws_size >= need_packed) {
        pack_mask_kernel<<<dim3(2048), 256, 0, stream>>>((const unsigned*)mask, pmw);
        attn_kernel<1><<<dim3(S_LEN / 128, 16), 256, 0, stream>>>(
            Q, K, V, pmw, (const unsigned*)mask, O);
    } else {
        attn_kernel<0><<<dim3(S_LEN / 128, 16), 256, 0, stream>>>(
            Q, K, V, nullptr, (const unsigned*)mask, O);
    }
}